// Round 13
// baseline (715.170 us; speedup 1.0000x reference)
//
#include <hip/hip_runtime.h>

typedef __attribute__((ext_vector_type(8))) short bfrag;   // 8 x bf16
typedef __attribute__((ext_vector_type(4))) float ffrag;   // 4 x f32

union BFU { bfrag f; unsigned int u[4]; };

__device__ __forceinline__ unsigned int cvt_pk_bf16(float lo, float hi) {
    unsigned int r;
    asm("v_cvt_pk_bf16_f32 %0, %1, %2" : "=v"(r) : "v"(lo), "v"(hi));
    return r;
}
__device__ __forceinline__ unsigned short f2bf1(float x) {
    return (unsigned short)cvt_pk_bf16(x, x);
}

// ---- prep1: wlinT[h][e] = Wlin[e][h]; w2T[f2][f1] = W2[f1][f2] (bf16) ----
__global__ void prep1(const float* __restrict__ Wlin, const float* __restrict__ W2,
                      unsigned short* __restrict__ wlinT, unsigned short* __restrict__ w2T) {
    int idx = blockIdx.x * 256 + threadIdx.x;          // 0..32767
    { int e = idx >> 7, h = idx & 127; wlinT[h * 256 + e] = f2bf1(Wlin[idx]); }
    if (idx < 16384) { int a = idx >> 7, b = idx & 127; w2T[b * 128 + a] = f2bf1(W2[idx]); }
}

// ---- prep2: fold edge-LN affine into W1 ----
// hn@W1 = z@(g_edge*W1) + (b_edge@W1);  z=(h-mu)*rs
// w1gT[f][h] = bf16(g_edge[h]*W1[h][f]);  b1f[f] = b1[f] + sum_h b_edge[h]*W1[h][f]
__global__ void prep2(const float* __restrict__ W1, const float* __restrict__ g_edge,
                      const float* __restrict__ b_edge, const float* __restrict__ b1,
                      unsigned short* __restrict__ w1gT, float* __restrict__ b1f) {
    int f = threadIdx.x;
    float s = b1[f];
    for (int h = 0; h < 128; ++h) {
        float wv = W1[h * 128 + f];
        w1gT[f * 128 + h] = f2bf1(g_edge[h] * wv);
        s += b_edge[h] * wv;
    }
    b1f[f] = s;
}

// ---- fused kernel: 256 thr / 4 waves; wave owns 16 edge rows (block = 64 rows
// = 2 nodes). ALL compute transposed (C row = hidden dim, C col = edge row):
// thread (q,c) holds row rb+c, hdims {16t+4q+r}. Edge-LN = 2 shfl_xor, no LDS.
// Inter-GEMM transposes via PRIVATE per-wave LDS (in-order DS, no barrier).
// ONE __syncthreads per block (node merge).
// r9 fix: epilogue covers ALL 128 cols (two float4 per row per thread).
__global__ __launch_bounds__(256, 4) void fused_kernel(
    const float* __restrict__ ef, const int* __restrict__ mask,
    const unsigned short* __restrict__ wlinT,
    const unsigned short* __restrict__ w1gT,
    const unsigned short* __restrict__ w2T,
    const float* __restrict__ b_lin, const float* __restrict__ b1f,
    const float* __restrict__ b2, const float* __restrict__ g_node,
    const float* __restrict__ b_node,
    float* __restrict__ out_node, float* __restrict__ out_edge, int N) {

    __shared__ char lds[4 * 8704];     // per-wave slice: z bf16 [16][272B] @0,
                                       // gelu bf16 [16][272B] @4352, eo f32 [16][528B] @0
    __shared__ float nvlds[4][128];    // per-wave masked partial node sums

    const int tid = threadIdx.x;
    const int w = tid >> 6, l = tid & 63, q = l >> 4, c = l & 15;

    int rb_blk = blockIdx.x * 64;
    if (rb_blk + 64 > N * 32) rb_blk = N * 32 - 64;    // tail overlap, idempotent
    const int rb = rb_blk + w * 16;                     // wave's rows [rb, rb+16)

    char* Z  = lds + w * 8704;
    char* G  = Z + 4352;
    char* EO = Z;                                       // reused after G consumed

    // ---- GEMM1 (transposed): h8[t][r] = h[row=rb+c][hd=16t+4q+r] ----
    // A-frag = WlinT rows (hd), B-frag = ef rows read DIRECT from global (f32->bf16)
    ffrag h8[8] = {};
    const float* efrow = ef + (size_t)(rb + c) * 256;
    #pragma unroll 2
    for (int kk = 0; kk < 8; ++kk) {
        const float4* bp = (const float4*)(efrow + kk * 32 + 8 * q);
        float4 e0 = bp[0], e1 = bp[1];
        BFU bb;
        bb.u[0] = cvt_pk_bf16(e0.x, e0.y); bb.u[1] = cvt_pk_bf16(e0.z, e0.w);
        bb.u[2] = cvt_pk_bf16(e1.x, e1.y); bb.u[3] = cvt_pk_bf16(e1.z, e1.w);
        #pragma unroll
        for (int t = 0; t < 8; ++t) {
            bfrag a = *(const bfrag*)(wlinT + (16 * t + c) * 256 + kk * 32 + 8 * q);
            h8[t] = __builtin_amdgcn_mfma_f32_16x16x32_bf16(a, bb.f, h8[t], 0, 0, 0);
        }
    }

    // ---- + b_lin; edge-LN stats fully in-register (row = rb+c) ----
    float sum = 0.f, sq = 0.f;
    #pragma unroll
    for (int t = 0; t < 8; ++t)
        #pragma unroll
        for (int r = 0; r < 4; ++r) {
            float v = h8[t][r] + b_lin[16 * t + 4 * q + r];
            h8[t][r] = v;
            sum += v; sq += v * v;
        }
    sum += __shfl_xor(sum, 16); sum += __shfl_xor(sum, 32);
    sq  += __shfl_xor(sq, 16);  sq  += __shfl_xor(sq, 32);
    const float mu = sum * (1.f / 128.f);
    const float rs = rsqrtf(sq * (1.f / 128.f) - mu * mu + 1e-5f);

    // ---- z = (h-mu)*rs -> Z (bf16, row-major [c][hd], pad 272B) ----
    #pragma unroll
    for (int t = 0; t < 8; ++t) {
        *(unsigned int*)(Z + c * 272 + 32 * t + 8 * q) =
            cvt_pk_bf16((h8[t][0] - mu) * rs, (h8[t][1] - mu) * rs);
        *(unsigned int*)(Z + c * 272 + 32 * t + 8 * q + 4) =
            cvt_pk_bf16((h8[t][2] - mu) * rs, (h8[t][3] - mu) * rs);
    }

    // ---- FFN1 (transposed): acc2 = W1gT @ zT ----
    ffrag acc2[8] = {};
    #pragma unroll
    for (int kk = 0; kk < 4; ++kk) {
        bfrag zb = *(const bfrag*)(Z + c * 272 + kk * 64 + 16 * q);
        #pragma unroll
        for (int t = 0; t < 8; ++t) {
            bfrag a = *(const bfrag*)(w1gT + (16 * t + c) * 128 + kk * 32 + 8 * q);
            acc2[t] = __builtin_amdgcn_mfma_f32_16x16x32_bf16(a, zb, acc2[t], 0, 0, 0);
        }
    }

    // ---- gelu -> G ----
    #pragma unroll
    for (int t = 0; t < 8; ++t) {
        float gg[4];
        #pragma unroll
        for (int r = 0; r < 4; ++r) {
            float x = acc2[t][r] + b1f[16 * t + 4 * q + r];
            float y = 0.7978845608028654f * x * (1.f + 0.044715f * x * x);
            float e;
            asm("v_exp_f32 %0, %1" : "=v"(e) : "v"(-2.885390081777927f * y));
            float rcp;
            asm("v_rcp_f32 %0, %1" : "=v"(rcp) : "v"(1.f + e));
            gg[r] = x * rcp;
        }
        *(unsigned int*)(G + c * 272 + 32 * t + 8 * q)     = cvt_pk_bf16(gg[0], gg[1]);
        *(unsigned int*)(G + c * 272 + 32 * t + 8 * q + 4) = cvt_pk_bf16(gg[2], gg[3]);
    }

    // ---- FFN2 (transposed): acc3 = W2T @ gT ----
    ffrag acc3[8] = {};
    #pragma unroll
    for (int kk = 0; kk < 4; ++kk) {
        bfrag gb = *(const bfrag*)(G + c * 272 + kk * 64 + 16 * q);
        #pragma unroll
        for (int t = 0; t < 8; ++t) {
            bfrag a = *(const bfrag*)(w2T + (16 * t + c) * 128 + kk * 32 + 8 * q);
            acc3[t] = __builtin_amdgcn_mfma_f32_16x16x32_bf16(a, gb, acc3[t], 0, 0, 0);
        }
    }

    // ---- eo = acc3 + b2 + h (residual) -> EO (f32 [16 rows][528B]) ----
    #pragma unroll
    for (int t = 0; t < 8; ++t)
        #pragma unroll
        for (int r = 0; r < 4; ++r) {
            float v = acc3[t][r] + b2[16 * t + 4 * q + r] + h8[t][r];
            *(float*)(EO + c * 528 + (16 * t + 4 * q + r) * 4) = v;
        }

    // ---- coalesced eo store + masked aggregation: 2 float4 per row per thread
    // (cols 4c..4c+3 and 64+4c..64+4c+3) -> all 128 cols covered (r9 fix) ----
    float4 nva = make_float4(0.f, 0.f, 0.f, 0.f);
    float4 nvb = make_float4(0.f, 0.f, 0.f, 0.f);
    float* eob = out_edge + (size_t)rb * 128;
    #pragma unroll
    for (int rr = 0; rr < 4; ++rr) {
        int row = rr * 4 + q;
        float4 va = *(const float4*)(EO + row * 528 + c * 16);
        float4 vb = *(const float4*)(EO + row * 528 + 256 + c * 16);
        *(float4*)(eob + row * 128 + c * 4)      = va;
        *(float4*)(eob + row * 128 + 64 + c * 4) = vb;
        float m = (mask[rb + row] != 0) ? 1.f : 0.f;
        nva.x += m * va.x; nva.y += m * va.y; nva.z += m * va.z; nva.w += m * va.w;
        nvb.x += m * vb.x; nvb.y += m * vb.y; nvb.z += m * vb.z; nvb.w += m * vb.w;
    }
    nva.x += __shfl_xor(nva.x, 16); nva.x += __shfl_xor(nva.x, 32);
    nva.y += __shfl_xor(nva.y, 16); nva.y += __shfl_xor(nva.y, 32);
    nva.z += __shfl_xor(nva.z, 16); nva.z += __shfl_xor(nva.z, 32);
    nva.w += __shfl_xor(nva.w, 16); nva.w += __shfl_xor(nva.w, 32);
    nvb.x += __shfl_xor(nvb.x, 16); nvb.x += __shfl_xor(nvb.x, 32);
    nvb.y += __shfl_xor(nvb.y, 16); nvb.y += __shfl_xor(nvb.y, 32);
    nvb.z += __shfl_xor(nvb.z, 16); nvb.z += __shfl_xor(nvb.z, 32);
    nvb.w += __shfl_xor(nvb.w, 16); nvb.w += __shfl_xor(nvb.w, 32);
    if (q == 0) {
        *(float4*)(&nvlds[w][4 * c])      = nva;
        *(float4*)(&nvlds[w][64 + 4 * c]) = nvb;
    }
    __syncthreads();                                   // the ONLY block barrier

    // ---- node LN: wave 0 -> node rb_blk/32, wave 1 -> +1 ----
    if (w < 2) {
        float v0 = nvlds[2 * w][l]      + nvlds[2 * w + 1][l];
        float v1 = nvlds[2 * w][64 + l] + nvlds[2 * w + 1][64 + l];
        float s = v0 + v1, qv = v0 * v0 + v1 * v1;
        #pragma unroll
        for (int d = 1; d < 64; d <<= 1) { s += __shfl_xor(s, d); qv += __shfl_xor(qv, d); }
        float mu2 = s * (1.f / 128.f);
        float rstd = rsqrtf(qv * (1.f / 128.f) - mu2 * mu2 + 1e-5f);
        size_t nb = ((size_t)(rb_blk >> 5) + w) * 128;
        out_node[nb + l]      = (v0 - mu2) * rstd * g_node[l]      + b_node[l];
        out_node[nb + 64 + l] = (v1 - mu2) * rstd * g_node[64 + l] + b_node[64 + l];
    }
}

extern "C" void kernel_launch(void* const* d_in, const int* in_sizes, int n_in,
                              void* d_out, int out_size, void* d_ws, size_t ws_size,
                              hipStream_t stream) {
    const float* ef     = (const float*)d_in[0];
    const int*   mask   = (const int*)d_in[1];
    const float* Wlin   = (const float*)d_in[2];
    const float* b_lin  = (const float*)d_in[3];
    const float* g_edge = (const float*)d_in[4];
    const float* b_edge = (const float*)d_in[5];
    const float* W1     = (const float*)d_in[6];
    const float* b1     = (const float*)d_in[7];
    const float* W2     = (const float*)d_in[8];
    const float* b2     = (const float*)d_in[9];
    const float* g_node = (const float*)d_in[10];
    const float* b_node = (const float*)d_in[11];

    int N = in_sizes[0] / (32 * 256);

    unsigned short* wlinT = (unsigned short*)d_ws;          // [128][256] bf16
    unsigned short* w1gT  = wlinT + 128 * 256;              // [128][128] bf16 (g-folded)
    unsigned short* w2T   = w1gT + 128 * 128;               // [128][128] bf16
    float*          b1f   = (float*)(w2T + 128 * 128);      // [128] f32

    float* out_node = (float*)d_out;
    float* out_edge = out_node + (size_t)N * 128;

    prep1<<<128, 256, 0, stream>>>(Wlin, W2, wlinT, w2T);
    prep2<<<1, 128, 0, stream>>>(W1, g_edge, b_edge, b1, w1gT, b1f);
    int nblocks = (N * 32 + 63) / 64;
    fused_kernel<<<nblocks, 256, 0, stream>>>(ef, mask, wlinT, w1gT, w2T,
                                              b_lin, b1f, b2, g_node, b_node,
                                              out_node, out_edge, N);
}